// Round 3
// baseline (12670.950 us; speedup 1.0000x reference)
//
#include <hip/hip_runtime.h>
#include <math.h>

#define NTOK 2048           // B*N
#define DIMC 1024

typedef __attribute__((ext_vector_type(4))) float f32x4;

__device__ __forceinline__ float bf2f(unsigned short u){ return __uint_as_float(((unsigned)u)<<16); }

// ---------------- weight stats: alpha=mean(w), beta-sum=sum|w| ----------------
__global__ __launch_bounds__(256) void k_wstats(const float* __restrict__ w1, const float* __restrict__ w2,
                                                double* __restrict__ dsum, double* __restrict__ dabs){
  const int mat = blockIdx.y;
  const float* wp = (mat < 6) ? (w1 + (size_t)mat*1048576) : (w2 + (size_t)(mat-6)*1048576);
  const f32x4* wv = (const f32x4*)wp + (size_t)blockIdx.x*8192;
  double s = 0.0, a = 0.0;
  for (int j = 0; j < 32; j++){
    f32x4 v = wv[j*256 + threadIdx.x];
    s += (double)v.x + (double)v.y + (double)v.z + (double)v.w;
    a += (double)fabsf(v.x) + (double)fabsf(v.y) + (double)fabsf(v.z) + (double)fabsf(v.w);
  }
  for (int d = 1; d < 64; d <<= 1){ s += __shfl_xor(s, d); a += __shfl_xor(a, d); }
  __shared__ double red[8];
  const int w = threadIdx.x >> 6;
  if ((threadIdx.x & 63) == 0){ red[w*2] = s; red[w*2+1] = a; }
  __syncthreads();
  if (threadIdx.x == 0){
    double S = red[0]+red[2]+red[4]+red[6], A = red[1]+red[3]+red[5]+red[7];
    atomicAdd(&dsum[mat], S);
    atomicAdd(&dabs[mat], A);
  }
}

// ---------------- binarize weights to bf16 {-1,0,+1} (exact values) ----------------
__global__ __launch_bounds__(256) void k_binarize(const float* __restrict__ w1, const float* __restrict__ w2,
                                                  const double* __restrict__ dsum, unsigned short* __restrict__ wb){
  const int blk = blockIdx.x;          // 6144 blocks, 512 per matrix
  const int mat = blk >> 9;
  const float alpha = (float)(dsum[mat] * (1.0/1048576.0));
  const float* wp = (mat < 6) ? (w1 + (size_t)mat*1048576) : (w2 + (size_t)(mat-6)*1048576);
  const size_t off = (size_t)(blk & 511)*2048 + (size_t)threadIdx.x*8;
  f32x4 v0 = *(const f32x4*)(wp + off), v1 = *(const f32x4*)(wp + off + 4);
  float vv[8] = {v0.x,v0.y,v0.z,v0.w,v1.x,v1.y,v1.z,v1.w};
  unsigned short o[8];
  for (int e = 0; e < 8; e++){
    float d = vv[e] - alpha;
    o[e] = d > 0.f ? 0x3F80u : (d < 0.f ? 0xBF80u : 0u);
  }
  uint4 pk;
  pk.x = (unsigned)o[0] | ((unsigned)o[1]<<16);
  pk.y = (unsigned)o[2] | ((unsigned)o[3]<<16);
  pk.z = (unsigned)o[4] | ((unsigned)o[5]<<16);
  pk.w = (unsigned)o[6] | ((unsigned)o[7]<<16);
  *(uint4*)(wb + (size_t)mat*1048576 + off) = pk;
}

// ---------------- NAIVE fp32 attention + residual (bisection golden) ----------------
// grid (4, 32), block 256. One thread = one q row of one (b,h). Online softmax,
// all fp32, K/V tiles staged to LDS. q pre-scaled by dh^-0.5 = 0.125.
__global__ __launch_bounds__(256) void k_attn_naive(const float* __restrict__ xin, float* __restrict__ xout){
  __shared__ float kt[64][65];
  const int b = blockIdx.y >> 4, h = blockIdx.y & 15;
  const int row = blockIdx.x*256 + threadIdx.x;          // 0..1023 within (b,h)
  const float* xb = xin + (size_t)b*1048576 + h*64;
  float q[64], acc[64];
  const float* qr = xb + (size_t)row*DIMC;
  #pragma unroll
  for (int d = 0; d < 64; d++){ q[d] = qr[d]*0.125f; acc[d] = 0.f; }
  float m = -1e30f, l = 0.f;
  #pragma unroll 1
  for (int t = 0; t < 16; t++){
    __syncthreads();
    { // stage 64 keys x 64 dims
      const int r = threadIdx.x >> 2, c = (threadIdx.x & 3)*16;
      const float* src = xb + (size_t)(t*64+r)*DIMC + c;
      #pragma unroll
      for (int e = 0; e < 16; e++) kt[r][c+e] = src[e];
    }
    __syncthreads();
    #pragma unroll 1
    for (int j = 0; j < 64; j++){
      float s = 0.f;
      #pragma unroll
      for (int d = 0; d < 64; d++) s += q[d]*kt[j][d];
      const float mn  = fmaxf(m, s);
      const float fac = __expf(m - mn);
      const float p   = __expf(s - mn);
      l = l*fac + p;
      #pragma unroll
      for (int d = 0; d < 64; d++) acc[d] = acc[d]*fac + p*kt[j][d];
      m = mn;
    }
  }
  const float inv = 1.f/l;
  float* orow = xout + (size_t)b*1048576 + (size_t)row*DIMC + h*64;
  const float* irow = xin + (size_t)b*1048576 + (size_t)row*DIMC + h*64;
  #pragma unroll
  for (int d = 0; d < 64; d++) orow[d] = acc[d]*inv + irow[d];
}

// ---------------- layernorm, fp32 out, optional gamma=max|h| ----------------
__global__ __launch_bounds__(256) void k_ln(const float* __restrict__ x, const float* __restrict__ gg,
                                            const float* __restrict__ bb, float* __restrict__ out,
                                            unsigned* __restrict__ gamma){
  const int row = blockIdx.x*4 + (threadIdx.x>>6);
  const int lane = threadIdx.x & 63;
  const f32x4* xr = (const f32x4*)(x + (size_t)row*DIMC);
  f32x4 v[4];
  float s = 0.f, q = 0.f;
  for (int j = 0; j < 4; j++){
    v[j] = xr[j*64 + lane];
    s += v[j].x+v[j].y+v[j].z+v[j].w;
    q += v[j].x*v[j].x + v[j].y*v[j].y + v[j].z*v[j].z + v[j].w*v[j].w;
  }
  for (int d = 1; d < 64; d <<= 1){ s += __shfl_xor(s,d); q += __shfl_xor(q,d); }
  const float mean = s * (1.f/1024.f);
  const float var  = q * (1.f/1024.f) - mean*mean;
  const float rstd = rsqrtf(var + 1e-5f);
  const f32x4* g4 = (const f32x4*)gg;
  const f32x4* b4 = (const f32x4*)bb;
  float amax = 0.f;
  for (int j = 0; j < 4; j++){
    f32x4 gv = g4[j*64+lane], bv = b4[j*64+lane];
    f32x4 ov;
    ov.x = (v[j].x-mean)*rstd*gv.x + bv.x;
    ov.y = (v[j].y-mean)*rstd*gv.y + bv.y;
    ov.z = (v[j].z-mean)*rstd*gv.z + bv.z;
    ov.w = (v[j].w-mean)*rstd*gv.w + bv.w;
    ((f32x4*)out)[(size_t)row*256 + j*64 + lane] = ov;
    amax = fmaxf(amax, fmaxf(fmaxf(fabsf(ov.x),fabsf(ov.y)), fmaxf(fabsf(ov.z),fabsf(ov.w))));
  }
  if (gamma){
    for (int d = 1; d < 64; d <<= 1) amax = fmaxf(amax, __shfl_xor(amax,d));
    if (lane == 0) atomicMax(gamma, __float_as_uint(amax));
  }
}

// ---------------- in-place absmax quantization (fp32) ----------------
__global__ __launch_bounds__(256) void k_quant_f(float* __restrict__ hq, const unsigned* __restrict__ gbits){
  const float sc = 128.f / __uint_as_float(*gbits);
  const size_t i = (size_t)blockIdx.x*256 + threadIdx.x;
  f32x4 v = ((f32x4*)hq)[i];
  v.x = fminf(fmaxf(v.x*sc, -127.99999f), 127.99999f);
  v.y = fminf(fmaxf(v.y*sc, -127.99999f), 127.99999f);
  v.z = fminf(fmaxf(v.z*sc, -127.99999f), 127.99999f);
  v.w = fminf(fmaxf(v.w*sc, -127.99999f), 127.99999f);
  ((f32x4*)hq)[i] = v;
}

// ---------------- NAIVE fp32 bitlinear GEMM (bisection golden) ----------------
// C[2048,1024] = Aq(fp32) . Wb^T (wb bf16 {-1,0,+1} -> exact fp32)
// grid (16 ntiles, 32 mtiles), block 256: tx=tid&15 -> 4 cols, ty=tid>>4 -> 4 rows
// MODE 0: y=acc*scale -> exact GELU -> fp32 out + gamma_out atomicMax
// MODE 1: y=acc*scale + residual (fp32, in place)
template<int MODE>
__global__ __launch_bounds__(256) void k_gemm_naive(const float* __restrict__ Aq,
                                                    const unsigned short* __restrict__ Bw,
                                                    float* __restrict__ outp,
                                                    const double* __restrict__ dabs_slot,
                                                    const unsigned* __restrict__ gin,
                                                    unsigned* __restrict__ gout){
  __shared__ float As[64][17];
  __shared__ float Bs[64][17];
  const int tid = threadIdx.x, tx = tid & 15, ty = tid >> 4;
  const int m0 = blockIdx.y*64, n0 = blockIdx.x*64;
  const float scale = (float)(*dabs_slot * (1.0/1048576.0)) * __uint_as_float(*gin) * (1.f/128.f);
  float c[4][4] = {};
  #pragma unroll 1
  for (int k0 = 0; k0 < 1024; k0 += 16){
    __syncthreads();
    { // stage A 64x16 and B 64x16
      const int r = tid >> 2, kq = (tid & 3)*4;
      const float* asrc = Aq + (size_t)(m0 + r)*1024 + k0 + kq;
      const unsigned short* bsrc = Bw + (size_t)(n0 + r)*1024 + k0 + kq;
      #pragma unroll
      for (int e = 0; e < 4; e++){
        As[r][kq+e] = asrc[e];
        Bs[r][kq+e] = bf2f(bsrc[e]);
      }
    }
    __syncthreads();
    #pragma unroll
    for (int kk = 0; kk < 16; kk++){
      float a[4], b[4];
      #pragma unroll
      for (int i = 0; i < 4; i++) a[i] = As[ty*4+i][kk];
      #pragma unroll
      for (int j = 0; j < 4; j++) b[j] = Bs[tx*4+j][kk];
      #pragma unroll
      for (int i = 0; i < 4; i++)
        #pragma unroll
        for (int j = 0; j < 4; j++)
          c[i][j] += a[i]*b[j];
    }
  }
  float amax = 0.f;
  #pragma unroll
  for (int i = 0; i < 4; i++)
    #pragma unroll
    for (int j = 0; j < 4; j++){
      const int rr = m0 + ty*4 + i, cc = n0 + tx*4 + j;
      float vv = c[i][j] * scale;
      if (MODE == 0){
        vv = 0.5f*vv*(1.f + erff(vv*0.70710678118f));
        outp[(size_t)rr*1024 + cc] = vv;
        amax = fmaxf(amax, fabsf(vv));
      } else {
        outp[(size_t)rr*1024 + cc] += vv;
      }
    }
  if (MODE == 0){
    for (int d = 1; d < 64; d <<= 1) amax = fmaxf(amax, __shfl_xor(amax,d));
    if ((tid & 63) == 0) atomicMax(gout, __float_as_uint(amax));
  }
}

extern "C" void kernel_launch(void* const* d_in, const int* in_sizes, int n_in,
                              void* d_out, int out_size, void* d_ws, size_t ws_size,
                              hipStream_t stream){
  const float* x_in = (const float*)d_in[0];
  const float* ln_g = (const float*)d_in[1];
  const float* ln_b = (const float*)d_in[2];
  const float* w1   = (const float*)d_in[3];
  const float* w2   = (const float*)d_in[4];
  const float* fg   = (const float*)d_in[5];
  const float* fb   = (const float*)d_in[6];

  char* ws = (char*)d_ws;
  double*   dsum  = (double*)ws;            // 12
  double*   dabs  = (double*)(ws + 96);     // 12
  unsigned* gbits = (unsigned*)(ws + 192);  // 12
  unsigned short* wb = (unsigned short*)(ws + 256);       // 12 * 1M bf16 = 24 MB
  size_t o = 256 + 12ull*1048576ull*2ull;
  float* xA = (float*)(ws + o); o += (size_t)NTOK*DIMC*4;
  float* xB = (float*)(ws + o); o += (size_t)NTOK*DIMC*4;
  float* hf = (float*)(ws + o); o += (size_t)NTOK*DIMC*4;
  float* gf = (float*)(ws + o); o += (size_t)NTOK*DIMC*4;

  hipMemsetAsync(ws, 0, 256, stream);
  k_wstats  <<<dim3(32,12), 256, 0, stream>>>(w1, w2, dsum, dabs);
  k_binarize<<<6144,        256, 0, stream>>>(w1, w2, dsum, wb);

  const float* xc = x_in;
  for (int i = 0; i < 6; i++){
    float* xn = (i & 1) ? xB : xA;
    k_attn_naive<<<dim3(4,32), 256, 0, stream>>>(xc, xn);
    k_ln<<<512, 256, 0, stream>>>(xn, ln_g + (size_t)i*1024, ln_b + (size_t)i*1024, hf, &gbits[2*i]);
    k_quant_f<<<2048, 256, 0, stream>>>(hf, &gbits[2*i]);
    k_gemm_naive<0><<<dim3(16,32), 256, 0, stream>>>(hf, wb + (size_t)i*1048576, gf,
                                                     &dabs[i], &gbits[2*i], &gbits[2*i+1]);
    k_quant_f<<<2048, 256, 0, stream>>>(gf, &gbits[2*i+1]);
    k_gemm_naive<1><<<dim3(16,32), 256, 0, stream>>>(gf, wb + (size_t)(6+i)*1048576, xn,
                                                     &dabs[6+i], &gbits[2*i+1], nullptr);
    xc = xn;
  }
  k_ln<<<512, 256, 0, stream>>>(xc, fg, fb, (float*)d_out, nullptr);
}

// Round 4
// 1018.899 us; speedup vs baseline: 12.4359x; 12.4359x over previous
//
#include <hip/hip_runtime.h>
#include <math.h>

#define NTOK 2048           // B*N
#define DIMC 1024

typedef __attribute__((ext_vector_type(4))) float f32x4;
typedef __attribute__((ext_vector_type(8))) _Float16 f16x8;
typedef __attribute__((ext_vector_type(4))) _Float16 f16x4;

__device__ __forceinline__ f32x4 mfma16h(f16x8 a, f16x8 b, f32x4 c){
  return __builtin_amdgcn_mfma_f32_16x16x32_f16(a, b, c, 0, 0, 0);
}
__device__ __forceinline__ void gload_lds16(const void* g, void* l){
  __builtin_amdgcn_global_load_lds((const __attribute__((address_space(1))) void*)g,
                                   (__attribute__((address_space(3))) void*)l, 16, 0, 0);
}

// ---------------- weight stats: alpha=mean(w), beta-sum=sum|w| ----------------
__global__ __launch_bounds__(256) void k_wstats(const float* __restrict__ w1, const float* __restrict__ w2,
                                                double* __restrict__ dsum, double* __restrict__ dabs){
  const int mat = blockIdx.y;
  const float* wp = (mat < 6) ? (w1 + (size_t)mat*1048576) : (w2 + (size_t)(mat-6)*1048576);
  const f32x4* wv = (const f32x4*)wp + (size_t)blockIdx.x*8192;
  double s = 0.0, a = 0.0;
  for (int j = 0; j < 32; j++){
    f32x4 v = wv[j*256 + threadIdx.x];
    s += (double)v.x + (double)v.y + (double)v.z + (double)v.w;
    a += (double)fabsf(v.x) + (double)fabsf(v.y) + (double)fabsf(v.z) + (double)fabsf(v.w);
  }
  for (int d = 1; d < 64; d <<= 1){ s += __shfl_xor(s, d); a += __shfl_xor(a, d); }
  __shared__ double red[8];
  const int w = threadIdx.x >> 6;
  if ((threadIdx.x & 63) == 0){ red[w*2] = s; red[w*2+1] = a; }
  __syncthreads();
  if (threadIdx.x == 0){
    double S = red[0]+red[2]+red[4]+red[6], A = red[1]+red[3]+red[5]+red[7];
    atomicAdd(&dsum[mat], S);
    atomicAdd(&dabs[mat], A);
  }
}

// ---------------- binarize weights to fp16 {-1,0,+1} (exact values) ----------------
__global__ __launch_bounds__(256) void k_binarize(const float* __restrict__ w1, const float* __restrict__ w2,
                                                  const double* __restrict__ dsum, unsigned short* __restrict__ wb){
  const int blk = blockIdx.x;          // 6144 blocks, 512 per matrix
  const int mat = blk >> 9;
  const float alpha = (float)(dsum[mat] * (1.0/1048576.0));
  const float* wp = (mat < 6) ? (w1 + (size_t)mat*1048576) : (w2 + (size_t)(mat-6)*1048576);
  const size_t off = (size_t)(blk & 511)*2048 + (size_t)threadIdx.x*8;
  f32x4 v0 = *(const f32x4*)(wp + off), v1 = *(const f32x4*)(wp + off + 4);
  float vv[8] = {v0.x,v0.y,v0.z,v0.w,v1.x,v1.y,v1.z,v1.w};
  unsigned short o[8];
  for (int e = 0; e < 8; e++){
    float d = vv[e] - alpha;
    o[e] = d > 0.f ? 0x3C00u : (d < 0.f ? 0xBC00u : 0u);   // fp16 +1/-1/0
  }
  uint4 pk;
  pk.x = (unsigned)o[0] | ((unsigned)o[1]<<16);
  pk.y = (unsigned)o[2] | ((unsigned)o[3]<<16);
  pk.z = (unsigned)o[4] | ((unsigned)o[5]<<16);
  pk.w = (unsigned)o[6] | ((unsigned)o[7]<<16);
  *(uint4*)(wb + (size_t)mat*1048576 + off) = pk;
}

// ---------------- flash attention + residual, split-fp16 MFMA everywhere ----------------
// grid (16 qtiles, 32 bh), 256 threads. q=k=v=x. out = softmax(QK^T/8)V + x
// Q,K,P,V all kept as fp16 hi+lo pairs; every matmul is a 3-term (or 2-term) split
// so injected noise ~2^-22 relative == fp32-serial level. (This net is chaotic:
// bf16/fp16 single-pass anywhere saturates the output error at ~3.5 — rounds 1-3.)
__global__ __launch_bounds__(256) void k_attn(const float* __restrict__ xin, float* __restrict__ xout){
  __shared__ _Float16 qsh[64*72], qsl[64*72];
  __shared__ _Float16 ksh[64*72], ksl[64*72];
  __shared__ _Float16 vth[64*72], vtl[64*72];
  __shared__ _Float16 psh[64*72], psl[64*72];
  const int tid = threadIdx.x, w = tid>>6, l = tid&63, g = l>>4, r16 = l&15;
  const int qt = blockIdx.x, bh = blockIdx.y, b = bh>>4, h = bh&15;
  const float* xb = xin + (size_t)b*1048576 + h*64;
  const int q0 = qt*64;
  { // stage Q (scaled by dh^-0.5 = 0.125 before split)
    const int r = tid>>2, c4 = tid&3;
    const float* src = xb + (size_t)(q0+r)*DIMC + c4*16;
    for (int j = 0; j < 4; j++){
      f32x4 v = *(const f32x4*)(src + j*4);
      int d = c4*16 + j*4;
      float vv[4] = {v.x,v.y,v.z,v.w};
      for (int e = 0; e < 4; e++){
        float q = vv[e]*0.125f;
        _Float16 hi = (_Float16)q;
        qsh[r*72+d+e] = hi;
        qsl[r*72+d+e] = (_Float16)(q - (float)hi);
      }
    }
  }
  __syncthreads();
  const f16x8 aqh0 = *(const f16x8*)&qsh[(w*16+r16)*72 + g*8];
  const f16x8 aqh1 = *(const f16x8*)&qsh[(w*16+r16)*72 + 32 + g*8];
  const f16x8 aql0 = *(const f16x8*)&qsl[(w*16+r16)*72 + g*8];
  const f16x8 aql1 = *(const f16x8*)&qsl[(w*16+r16)*72 + 32 + g*8];
  float mI[4], lI[4]; f32x4 acc[4];
  for (int i = 0; i < 4; i++){ mI[i] = -1e30f; lI[i] = 0.f; acc[i] = (f32x4){0.f,0.f,0.f,0.f}; }
  for (int t = 0; t < 16; t++){
    __syncthreads();
    { // stage 64-key tile: K split [key][d], V split [d][key]
      const int r = tid>>2, c4 = tid&3;
      const float* src = xb + (size_t)(t*64+r)*DIMC + c4*16;
      for (int j = 0; j < 4; j++){
        f32x4 v = *(const f32x4*)(src + j*4);
        int d = c4*16 + j*4;
        float vv[4] = {v.x,v.y,v.z,v.w};
        for (int e = 0; e < 4; e++){
          float kx = vv[e];
          _Float16 hi = (_Float16)kx;
          _Float16 lo = (_Float16)(kx - (float)hi);
          ksh[r*72+d+e] = hi;
          ksl[r*72+d+e] = lo;
          vth[(d+e)*72+r] = hi;
          vtl[(d+e)*72+r] = lo;
        }
      }
    }
    __syncthreads();
    // QK^T : S[q][key], 3-term split (drop Ql*Kl ~ 2^-22)
    f32x4 s[4];
    for (int c = 0; c < 4; c++){
      const f16x8 bh0 = *(const f16x8*)&ksh[(c*16+r16)*72 + g*8];
      const f16x8 bh1 = *(const f16x8*)&ksh[(c*16+r16)*72 + 32 + g*8];
      const f16x8 bl0 = *(const f16x8*)&ksl[(c*16+r16)*72 + g*8];
      const f16x8 bl1 = *(const f16x8*)&ksl[(c*16+r16)*72 + 32 + g*8];
      f32x4 z = (f32x4){0.f,0.f,0.f,0.f};
      z = mfma16h(aqh0, bh0, z);
      z = mfma16h(aqh1, bh1, z);
      z = mfma16h(aql0, bh0, z);
      z = mfma16h(aql1, bh1, z);
      z = mfma16h(aqh0, bl0, z);
      z = mfma16h(aqh1, bl1, z);
      s[c] = z;
    }
    // online softmax (rows = g*4+i, cols across the 16-lane group)
    float rmax[4], rsum[4], fac[4];
    for (int i = 0; i < 4; i++) rmax[i] = fmaxf(fmaxf(s[0][i],s[1][i]), fmaxf(s[2][i],s[3][i]));
    for (int d = 1; d < 16; d <<= 1)
      for (int i = 0; i < 4; i++) rmax[i] = fmaxf(rmax[i], __shfl_xor(rmax[i], d));
    for (int i = 0; i < 4; i++){
      float mn = fmaxf(mI[i], rmax[i]);
      fac[i] = __expf(mI[i] - mn);
      mI[i] = mn; rsum[i] = 0.f;
    }
    for (int c = 0; c < 4; c++)
      for (int i = 0; i < 4; i++){
        float p = __expf(s[c][i] - mI[i]);
        _Float16 ph = (_Float16)p;
        _Float16 pl = (_Float16)(p - (float)ph);
        psh[(w*16 + g*4 + i)*72 + c*16 + r16] = ph;
        psl[(w*16 + g*4 + i)*72 + c*16 + r16] = pl;
        rsum[i] += p;                 // P is ~exact now; sum fp32 p directly
      }
    for (int d = 1; d < 16; d <<= 1)
      for (int i = 0; i < 4; i++) rsum[i] += __shfl_xor(rsum[i], d);
    for (int i = 0; i < 4; i++) lI[i] = lI[i]*fac[i] + rsum[i];
    for (int dc = 0; dc < 4; dc++)
      for (int i = 0; i < 4; i++) acc[dc][i] *= fac[i];
    __syncthreads();   // conservative: make P rows visible before PV reads
    // PV : 3-term split (drop Pl*Vl)
    for (int ks = 0; ks < 2; ks++){
      const f16x8 aph = *(const f16x8*)&psh[(w*16+r16)*72 + ks*32 + g*8];
      const f16x8 apl = *(const f16x8*)&psl[(w*16+r16)*72 + ks*32 + g*8];
      for (int dc = 0; dc < 4; dc++){
        const f16x8 bvh = *(const f16x8*)&vth[(dc*16+r16)*72 + ks*32 + g*8];
        const f16x8 bvl = *(const f16x8*)&vtl[(dc*16+r16)*72 + ks*32 + g*8];
        acc[dc] = mfma16h(aph, bvh, acc[dc]);
        acc[dc] = mfma16h(apl, bvh, acc[dc]);
        acc[dc] = mfma16h(aph, bvl, acc[dc]);
      }
    }
  }
  for (int dc = 0; dc < 4; dc++)
    for (int i = 0; i < 4; i++){
      int row = q0 + w*16 + g*4 + i;
      size_t idx = (size_t)b*1048576 + (size_t)row*DIMC + h*64 + dc*16 + r16;
      xout[idx] = acc[dc][i]/lI[i] + xin[idx];
    }
}

// ---------------- layernorm, fp32 out, optional gamma=max|h| ----------------
__global__ __launch_bounds__(256) void k_ln(const float* __restrict__ x, const float* __restrict__ gg,
                                            const float* __restrict__ bb, float* __restrict__ out,
                                            unsigned* __restrict__ gamma){
  const int row = blockIdx.x*4 + (threadIdx.x>>6);
  const int lane = threadIdx.x & 63;
  const f32x4* xr = (const f32x4*)(x + (size_t)row*DIMC);
  f32x4 v[4];
  float s = 0.f, q = 0.f;
  for (int j = 0; j < 4; j++){
    v[j] = xr[j*64 + lane];
    s += v[j].x+v[j].y+v[j].z+v[j].w;
    q += v[j].x*v[j].x + v[j].y*v[j].y + v[j].z*v[j].z + v[j].w*v[j].w;
  }
  for (int d = 1; d < 64; d <<= 1){ s += __shfl_xor(s,d); q += __shfl_xor(q,d); }
  const float mean = s * (1.f/1024.f);
  const float var  = q * (1.f/1024.f) - mean*mean;
  const float rstd = rsqrtf(var + 1e-5f);
  const f32x4* g4 = (const f32x4*)gg;
  const f32x4* b4 = (const f32x4*)bb;
  float amax = 0.f;
  for (int j = 0; j < 4; j++){
    f32x4 gv = g4[j*64+lane], bv = b4[j*64+lane];
    f32x4 ov;
    ov.x = (v[j].x-mean)*rstd*gv.x + bv.x;
    ov.y = (v[j].y-mean)*rstd*gv.y + bv.y;
    ov.z = (v[j].z-mean)*rstd*gv.z + bv.z;
    ov.w = (v[j].w-mean)*rstd*gv.w + bv.w;
    ((f32x4*)out)[(size_t)row*256 + j*64 + lane] = ov;
    amax = fmaxf(amax, fmaxf(fmaxf(fabsf(ov.x),fabsf(ov.y)), fmaxf(fabsf(ov.z),fabsf(ov.w))));
  }
  if (gamma){
    for (int d = 1; d < 64; d <<= 1) amax = fmaxf(amax, __shfl_xor(amax,d));
    if (lane == 0) atomicMax(gamma, __float_as_uint(amax));
  }
}

// ---------------- absmax quantization + fp16 hi/lo split ----------------
__global__ __launch_bounds__(256) void k_quant_split(const float* __restrict__ src,
                                                     _Float16* __restrict__ qh, _Float16* __restrict__ ql,
                                                     const unsigned* __restrict__ gbits){
  const float sc = 128.f / __uint_as_float(*gbits);
  const size_t i = (size_t)blockIdx.x*256 + threadIdx.x;
  f32x4 v = ((const f32x4*)src)[i];
  float qv[4] = {v.x, v.y, v.z, v.w};
  f16x4 ph, pl;
  for (int e = 0; e < 4; e++){
    float q = fminf(fmaxf(qv[e]*sc, -127.99999f), 127.99999f);
    _Float16 hi = (_Float16)q;
    ph[e] = hi;
    pl[e] = (_Float16)(q - (float)hi);
  }
  ((f16x4*)qh)[i] = ph;
  ((f16x4*)ql)[i] = pl;
}

// ---------------- bitlinear GEMM: C[2048,1024] = (Ah+Al) . Wb^T, split-fp16 MFMA ----------------
// weights exact {-1,0,+1} fp16, activation 2-term split -> ~2^-22 accuracy
// MODE 0: y=acc*scale -> exact GELU -> fp32 out + gamma_out atomicMax
// MODE 1: y=acc*scale + residual (fp32, in place)
template<int MODE>
__global__ __launch_bounds__(256) void k_gemm(const _Float16* __restrict__ Ah, const _Float16* __restrict__ Al,
                                              const unsigned short* __restrict__ Bw,
                                              float* __restrict__ outp,
                                              const double* __restrict__ dabs_slot,
                                              const unsigned* __restrict__ gin,
                                              unsigned* __restrict__ gout){
  __shared__ _Float16 Ash[64*32], Asl[64*32];
  __shared__ _Float16 Bs[128*32];
  const int tid = threadIdx.x, w = tid>>6, l = tid&63, g = l>>4, r16 = l&15;
  const int m0 = blockIdx.y*64, n0 = blockIdx.x*128;
  const float scale = (float)(*dabs_slot * (1.0/1048576.0)) * __uint_as_float(*gin) * (1.f/128.f);
  f32x4 acc[4][2] = {};
  const int srow = l >> 2;        // 0..15 within a 16-row chunk
  const int sk   = (l & 3) * 8;   // k offset 0/8/16/24
  for (int k0 = 0; k0 < 1024; k0 += 32){
    __syncthreads();
    gload_lds16(Ah + (size_t)(m0 + w*16 + srow)*1024 + k0 + sk, Ash + w*512);
    gload_lds16(Al + (size_t)(m0 + w*16 + srow)*1024 + k0 + sk, Asl + w*512);
    for (int j = 0; j < 2; j++){
      int ch = w*2 + j;
      gload_lds16(Bw + (size_t)(n0 + ch*16 + srow)*1024 + k0 + sk, Bs + ch*512);
    }
    __syncthreads();
    f16x8 afh[4], afl[4], bfr[2];
    for (int m = 0; m < 4; m++){
      afh[m] = *(const f16x8*)&Ash[(m*16 + r16)*32 + g*8];
      afl[m] = *(const f16x8*)&Asl[(m*16 + r16)*32 + g*8];
    }
    for (int n = 0; n < 2; n++) bfr[n] = *(const f16x8*)&Bs[(w*32 + n*16 + r16)*32 + g*8];
    for (int m = 0; m < 4; m++)
      for (int n = 0; n < 2; n++){
        acc[m][n] = mfma16h(afh[m], bfr[n], acc[m][n]);
        acc[m][n] = mfma16h(afl[m], bfr[n], acc[m][n]);
      }
  }
  float amax = 0.f;
  for (int m = 0; m < 4; m++)
    for (int n = 0; n < 2; n++)
      for (int i = 0; i < 4; i++){
        int rr = m0 + m*16 + g*4 + i;
        int cc = n0 + w*32 + n*16 + r16;
        float vv = acc[m][n][i] * scale;
        if (MODE == 0){
          vv = 0.5f*vv*(1.f + erff(vv*0.70710678118f));
          outp[(size_t)rr*1024 + cc] = vv;
          amax = fmaxf(amax, fabsf(vv));
        } else {
          outp[(size_t)rr*1024 + cc] += vv;
        }
      }
  if (MODE == 0){
    for (int d = 1; d < 64; d <<= 1) amax = fmaxf(amax, __shfl_xor(amax,d));
    if (l == 0) atomicMax(gout, __float_as_uint(amax));
  }
}

extern "C" void kernel_launch(void* const* d_in, const int* in_sizes, int n_in,
                              void* d_out, int out_size, void* d_ws, size_t ws_size,
                              hipStream_t stream){
  const float* x_in = (const float*)d_in[0];
  const float* ln_g = (const float*)d_in[1];
  const float* ln_b = (const float*)d_in[2];
  const float* w1   = (const float*)d_in[3];
  const float* w2   = (const float*)d_in[4];
  const float* fg   = (const float*)d_in[5];
  const float* fb   = (const float*)d_in[6];

  char* ws = (char*)d_ws;
  double*   dsum  = (double*)ws;            // 12
  double*   dabs  = (double*)(ws + 96);     // 12
  unsigned* gbits = (unsigned*)(ws + 192);  // 12
  unsigned short* wb = (unsigned short*)(ws + 256);       // 12 * 1M fp16 = 24 MB
  size_t o = 256 + 12ull*1048576ull*2ull;
  float* xA = (float*)(ws + o); o += (size_t)NTOK*DIMC*4;
  float* xB = (float*)(ws + o); o += (size_t)NTOK*DIMC*4;
  float* hf = (float*)(ws + o); o += (size_t)NTOK*DIMC*4;   // LN out fp32
  float* gf = (float*)(ws + o); o += (size_t)NTOK*DIMC*4;   // GELU out fp32
  _Float16* Ah = (_Float16*)(ws + o); o += (size_t)NTOK*DIMC*2;
  _Float16* Al = (_Float16*)(ws + o); o += (size_t)NTOK*DIMC*2;
  _Float16* Gh = (_Float16*)(ws + o); o += (size_t)NTOK*DIMC*2;
  _Float16* Gl = (_Float16*)(ws + o); o += (size_t)NTOK*DIMC*2;

  hipMemsetAsync(ws, 0, 256, stream);
  k_wstats  <<<dim3(32,12), 256, 0, stream>>>(w1, w2, dsum, dabs);
  k_binarize<<<6144,        256, 0, stream>>>(w1, w2, dsum, wb);

  const float* xc = x_in;
  for (int i = 0; i < 6; i++){
    float* xn = (i & 1) ? xB : xA;
    k_attn <<<dim3(16,32), 256, 0, stream>>>(xc, xn);
    k_ln<<<512, 256, 0, stream>>>(xn, ln_g + (size_t)i*1024, ln_b + (size_t)i*1024, hf, &gbits[2*i]);
    k_quant_split<<<2048, 256, 0, stream>>>(hf, Ah, Al, &gbits[2*i]);
    k_gemm<0><<<dim3(8,32), 256, 0, stream>>>(Ah, Al, wb + (size_t)i*1048576, gf,
                                              &dabs[i], &gbits[2*i], &gbits[2*i+1]);
    k_quant_split<<<2048, 256, 0, stream>>>(gf, Gh, Gl, &gbits[2*i+1]);
    k_gemm<1><<<dim3(8,32), 256, 0, stream>>>(Gh, Gl, wb + (size_t)(6+i)*1048576, xn,
                                              &dabs[6+i], &gbits[2*i+1], nullptr);
    xc = xn;
  }
  k_ln<<<512, 256, 0, stream>>>(xc, fg, fb, (float*)d_out, nullptr);
}

// Round 5
// 581.872 us; speedup vs baseline: 21.7762x; 1.7511x over previous
//
#include <hip/hip_runtime.h>
#include <math.h>

typedef __attribute__((ext_vector_type(4))) float f32x4;
typedef __attribute__((ext_vector_type(8))) _Float16 f16x8;

__device__ __forceinline__ f32x4 mfma16h(f16x8 a, f16x8 b, f32x4 c){
  return __builtin_amdgcn_mfma_f32_16x16x32_f16(a, b, c, 0, 0, 0);
}
__device__ __forceinline__ void gload_lds16(const void* g, void* l){
  __builtin_amdgcn_global_load_lds((const __attribute__((address_space(1))) void*)g,
                                   (__attribute__((address_space(3))) void*)l, 16, 0, 0);
}

// ---------------- weight stats: alpha=mean(w), beta-sum=sum|w| ----------------
__global__ __launch_bounds__(256) void k_wstats(const float* __restrict__ w1, const float* __restrict__ w2,
                                                double* __restrict__ dsum, double* __restrict__ dabs){
  const int mat = blockIdx.y;
  const float* wp = (mat < 6) ? (w1 + (size_t)mat*1048576) : (w2 + (size_t)(mat-6)*1048576);
  const f32x4* wv = (const f32x4*)wp + (size_t)blockIdx.x*8192;
  double s = 0.0, a = 0.0;
  for (int j = 0; j < 32; j++){
    f32x4 v = wv[j*256 + threadIdx.x];
    s += (double)v.x + (double)v.y + (double)v.z + (double)v.w;
    a += (double)fabsf(v.x) + (double)fabsf(v.y) + (double)fabsf(v.z) + (double)fabsf(v.w);
  }
  for (int d = 1; d < 64; d <<= 1){ s += __shfl_xor(s, d); a += __shfl_xor(a, d); }
  __shared__ double red[8];
  const int w = threadIdx.x >> 6;
  if ((threadIdx.x & 63) == 0){ red[w*2] = s; red[w*2+1] = a; }
  __syncthreads();
  if (threadIdx.x == 0){
    double S = red[0]+red[2]+red[4]+red[6], A = red[1]+red[3]+red[5]+red[7];
    atomicAdd(&dsum[mat], S);
    atomicAdd(&dabs[mat], A);
  }
}

// ---------------- binarize weights to fp16 {-1,0,+1}, swizzled GEMM-B layout ----------------
// layout: wb[mat][n][ (k&~63) + ((k&63) ^ 8*(n&7)) ]
__global__ __launch_bounds__(256) void k_binarize(const float* __restrict__ w1, const float* __restrict__ w2,
                                                  const double* __restrict__ dsum, _Float16* __restrict__ wb){
  const int blk = blockIdx.x;          // 6144 blocks, 512 per matrix
  const int mat = blk >> 9;
  const float alpha = (float)(dsum[mat] * (1.0/1048576.0));
  const float* wp = (mat < 6) ? (w1 + (size_t)mat*1048576) : (w2 + (size_t)(mat-6)*1048576);
  const size_t off = (size_t)(blk & 511)*2048 + (size_t)threadIdx.x*8;
  const int n = (int)(off >> 10), k = (int)(off & 1023);
  f32x4 v0 = *(const f32x4*)(wp + off), v1 = *(const f32x4*)(wp + off + 4);
  float vv[8] = {v0.x,v0.y,v0.z,v0.w,v1.x,v1.y,v1.z,v1.w};
  f16x8 pk;
  #pragma unroll
  for (int e = 0; e < 8; e++){
    float d = vv[e] - alpha;
    pk[e] = d > 0.f ? (_Float16)1.0f : (d < 0.f ? (_Float16)(-1.0f) : (_Float16)0.0f);
  }
  const size_t addr = (size_t)mat*1048576 + (size_t)n*1024 + (size_t)((k & ~63) + ((k & 63) ^ ((n&7)*8)));
  *(f16x8*)&wb[addr] = pk;
}

// ---------------- presplit: x (fp32) -> fp16 hi/lo in K-layout and V^T-layout ----------------
// K:  Kh/Kl[bh][n][ d ^ 8*(n&7) ]           (row n, 64 d)
// VT: Vh/Vl[bh][d][ t*64 + ((n&63) ^ 8*(d&7)) ]
__global__ __launch_bounds__(256) void k_presplit(const float* __restrict__ x,
                                                  _Float16* __restrict__ Kh, _Float16* __restrict__ Kl,
                                                  _Float16* __restrict__ Vh, _Float16* __restrict__ Vl){
  __shared__ _Float16 lh[64*72], ll[64*72];
  const int t = blockIdx.x, bh = blockIdx.y, b = bh>>4, h = bh&15;
  const int n = threadIdx.x>>2, c0 = (threadIdx.x&3)*16;
  const float* src = x + (size_t)b*1048576 + (size_t)(t*64+n)*1024 + h*64 + c0;
  const size_t kbase = ((size_t)bh*1024 + t*64 + n)*64;
  const int sw = (n&7)*8;
  #pragma unroll
  for (int j = 0; j < 2; j++){
    f32x4 v0 = *(const f32x4*)(src + j*8);
    f32x4 v1 = *(const f32x4*)(src + j*8 + 4);
    float vv[8] = {v0.x,v0.y,v0.z,v0.w,v1.x,v1.y,v1.z,v1.w};
    f16x8 Hv, Lv;
    #pragma unroll
    for (int e = 0; e < 8; e++){
      _Float16 hh = (_Float16)vv[e];
      Hv[e] = hh; Lv[e] = (_Float16)(vv[e] - (float)hh);
      const int d = c0 + j*8 + e;
      lh[d*72 + n] = Hv[e]; ll[d*72 + n] = Lv[e];
    }
    const int db = c0 + j*8;
    *(f16x8*)&Kh[kbase + (db ^ sw)] = Hv;
    *(f16x8*)&Kl[kbase + (db ^ sw)] = Lv;
  }
  __syncthreads();
  const int d = threadIdx.x>>2, n0c = (threadIdx.x&3)*16;
  const size_t vbase = ((size_t)bh*64 + d)*1024 + t*64;
  const int sw2 = (d&7)*8;
  #pragma unroll
  for (int j = 0; j < 2; j++){
    f16x8 Hv, Lv;
    #pragma unroll
    for (int e = 0; e < 8; e++){
      Hv[e] = lh[d*72 + n0c + j*8 + e];
      Lv[e] = ll[d*72 + n0c + j*8 + e];
    }
    const int nb = n0c + j*8;
    *(f16x8*)&Vh[vbase + (nb ^ sw2)] = Hv;
    *(f16x8*)&Vl[vbase + (nb ^ sw2)] = Lv;
  }
}

// ---------------- flash attention + residual, split-fp16 MFMA, presplit inputs ----------------
// grid (32 bh, 16 qt) so q-tiles sharing a K/V panel land on one XCD. 256 thr.
__global__ __launch_bounds__(256) void k_attn(const _Float16* __restrict__ Kh, const _Float16* __restrict__ Kl,
                                              const _Float16* __restrict__ Vh, const _Float16* __restrict__ Vl,
                                              const float* __restrict__ xin, float* __restrict__ xout){
  __shared__ _Float16 smb[24576];   // 48 KB
  _Float16* kt_h = smb;
  _Float16* kt_l = smb + 4096;
  _Float16* vt_h = smb + 8192;
  _Float16* vt_l = smb + 12288;
  _Float16* ps_h = smb + 16384;     // aliased: Q staging, then P hi
  _Float16* ps_l = smb + 20480;     // aliased: Q staging, then P lo
  const int tid = threadIdx.x, w = tid>>6, l = tid&63, g = l>>4, r16 = l&15;
  const int bh = blockIdx.x, qt = blockIdx.y, b = bh>>4, h = bh&15;
  const int swr = (r16&7)*8;
  // stage Q (rows qt*64..) into ps region, linear copy (swizzle already in global)
  const _Float16* Qsh = Kh + ((size_t)bh*1024 + qt*64)*64;
  const _Float16* Qsl = Kl + ((size_t)bh*1024 + qt*64)*64;
  #pragma unroll
  for (int j = 0; j < 2; j++){
    const int cb = (j*4 + w)*64;
    gload_lds16(Qsh + (size_t)(cb + l)*8, ps_h + cb*8);
    gload_lds16(Qsl + (size_t)(cb + l)*8, ps_l + cb*8);
  }
  __syncthreads();
  const int qrow = w*16 + r16;
  const f16x8 aqh0 = *(const f16x8*)&ps_h[qrow*64 + ((g*8) ^ swr)];
  const f16x8 aqh1 = *(const f16x8*)&ps_h[qrow*64 + ((32 + g*8) ^ swr)];
  const f16x8 aql0 = *(const f16x8*)&ps_l[qrow*64 + ((g*8) ^ swr)];
  const f16x8 aql1 = *(const f16x8*)&ps_l[qrow*64 + ((32 + g*8) ^ swr)];
  __syncthreads();
  float mI[4], lI[4]; f32x4 acc[4];
  #pragma unroll
  for (int i = 0; i < 4; i++){ mI[i] = -1e30f; lI[i] = 0.f; acc[i] = (f32x4){0.f,0.f,0.f,0.f}; }
  const _Float16* Kbh = Kh + (size_t)bh*65536;
  const _Float16* Kbl = Kl + (size_t)bh*65536;
  for (int t = 0; t < 16; t++){
    __syncthreads();
    #pragma unroll
    for (int j = 0; j < 2; j++){
      const int cb = (j*4 + w)*64;
      const int c  = cb + l;
      gload_lds16(Kbh + (size_t)t*4096 + (size_t)c*8, kt_h + cb*8);
      gload_lds16(Kbl + (size_t)t*4096 + (size_t)c*8, kt_l + cb*8);
      gload_lds16(Vh + ((size_t)bh*64 + (c>>3))*1024 + t*64 + (c&7)*8, vt_h + cb*8);
      gload_lds16(Vl + ((size_t)bh*64 + (c>>3))*1024 + t*64 + (c&7)*8, vt_l + cb*8);
    }
    __syncthreads();
    // QK^T, 3-term split, scale 0.125 applied post-MFMA (exact pow2)
    f32x4 s[4];
    #pragma unroll
    for (int c = 0; c < 4; c++){
      const int rk = c*16 + r16;
      const f16x8 kh0 = *(const f16x8*)&kt_h[rk*64 + ((g*8) ^ swr)];
      const f16x8 kh1 = *(const f16x8*)&kt_h[rk*64 + ((32+g*8) ^ swr)];
      const f16x8 kl0 = *(const f16x8*)&kt_l[rk*64 + ((g*8) ^ swr)];
      const f16x8 kl1 = *(const f16x8*)&kt_l[rk*64 + ((32+g*8) ^ swr)];
      f32x4 z = (f32x4){0.f,0.f,0.f,0.f};
      z = mfma16h(aqh0, kh0, z);
      z = mfma16h(aqh1, kh1, z);
      z = mfma16h(aql0, kh0, z);
      z = mfma16h(aql1, kh1, z);
      z = mfma16h(aqh0, kl0, z);
      z = mfma16h(aqh1, kl1, z);
      s[c] = z * 0.125f;
    }
    // online softmax (rows = g*4+i per lane-group)
    float rmax[4], rsum[4], fac[4];
    #pragma unroll
    for (int i = 0; i < 4; i++) rmax[i] = fmaxf(fmaxf(s[0][i],s[1][i]), fmaxf(s[2][i],s[3][i]));
    for (int d = 1; d < 16; d <<= 1)
      #pragma unroll
      for (int i = 0; i < 4; i++) rmax[i] = fmaxf(rmax[i], __shfl_xor(rmax[i], d));
    #pragma unroll
    for (int i = 0; i < 4; i++){
      float mn = fmaxf(mI[i], rmax[i]);
      fac[i] = __expf(mI[i] - mn);
      mI[i] = mn; rsum[i] = 0.f;
    }
    #pragma unroll
    for (int c = 0; c < 4; c++)
      #pragma unroll
      for (int i = 0; i < 4; i++){
        float p = __expf(s[c][i] - mI[i]);
        _Float16 ph = (_Float16)p;
        const int prow = w*16 + g*4 + i;
        const int pcol = (c*16 + r16) ^ ((2*g + (i>>1))*8);   // XOR by 8*((prow>>1)&7)
        ps_h[prow*64 + pcol] = ph;
        ps_l[prow*64 + pcol] = (_Float16)(p - (float)ph);
        rsum[i] += p;
      }
    for (int d = 1; d < 16; d <<= 1)
      #pragma unroll
      for (int i = 0; i < 4; i++) rsum[i] += __shfl_xor(rsum[i], d);
    #pragma unroll
    for (int i = 0; i < 4; i++) lI[i] = lI[i]*fac[i] + rsum[i];
    #pragma unroll
    for (int dc = 0; dc < 4; dc++)
      #pragma unroll
      for (int i = 0; i < 4; i++) acc[dc][i] *= fac[i];
    // PV, 3-term split; ps rows are wave-private (per-wave DS ordering suffices)
    const int psw = (r16>>1)*8;
    #pragma unroll
    for (int ks = 0; ks < 2; ks++){
      const f16x8 aph = *(const f16x8*)&ps_h[(w*16+r16)*64 + ((ks*32 + g*8) ^ psw)];
      const f16x8 apl = *(const f16x8*)&ps_l[(w*16+r16)*64 + ((ks*32 + g*8) ^ psw)];
      #pragma unroll
      for (int dc = 0; dc < 4; dc++){
        const int vr = dc*16 + r16;
        const f16x8 bvh = *(const f16x8*)&vt_h[vr*64 + ((ks*32 + g*8) ^ swr)];
        const f16x8 bvl = *(const f16x8*)&vt_l[vr*64 + ((ks*32 + g*8) ^ swr)];
        acc[dc] = mfma16h(aph, bvh, acc[dc]);
        acc[dc] = mfma16h(apl, bvh, acc[dc]);
        acc[dc] = mfma16h(aph, bvl, acc[dc]);
      }
    }
  }
  #pragma unroll
  for (int dc = 0; dc < 4; dc++)
    #pragma unroll
    for (int i = 0; i < 4; i++){
      const int row = qt*64 + w*16 + g*4 + i;
      const size_t idx = (size_t)b*1048576 + (size_t)row*1024 + h*64 + dc*16 + r16;
      xout[idx] = acc[dc][i]/lI[i] + xin[idx];
    }
}

// ---------------- layernorm; SPLIT=1 writes fp16 hi/lo in swizzled A-layout ----------------
template<int SPLIT>
__global__ __launch_bounds__(256) void k_ln(const float* __restrict__ x, const float* __restrict__ gg,
                                            const float* __restrict__ bb, float* __restrict__ outf,
                                            _Float16* __restrict__ Oh, _Float16* __restrict__ Ol){
  const int row = blockIdx.x*4 + (threadIdx.x>>6);
  const int lane = threadIdx.x & 63;
  const float* xr = x + (size_t)row*1024;
  f32x4 v[4];
  float s = 0.f, q = 0.f;
  #pragma unroll
  for (int c = 0; c < 2; c++){
    v[c*2]   = *(const f32x4*)(xr + c*512 + lane*8);
    v[c*2+1] = *(const f32x4*)(xr + c*512 + lane*8 + 4);
    #pragma unroll
    for (int e = 0; e < 4; e++){
      s += v[c*2][e] + v[c*2+1][e];
      q += v[c*2][e]*v[c*2][e] + v[c*2+1][e]*v[c*2+1][e];
    }
  }
  for (int d = 1; d < 64; d <<= 1){ s += __shfl_xor(s,d); q += __shfl_xor(q,d); }
  const float mean = s * (1.f/1024.f);
  const float var  = q * (1.f/1024.f) - mean*mean;
  const float rstd = rsqrtf(var + 1e-5f);
  #pragma unroll
  for (int c = 0; c < 2; c++){
    const int col = c*512 + lane*8;
    f32x4 g0 = *(const f32x4*)(gg + col), g1 = *(const f32x4*)(gg + col + 4);
    f32x4 b0 = *(const f32x4*)(bb + col), b1 = *(const f32x4*)(bb + col + 4);
    float h[8];
    #pragma unroll
    for (int e = 0; e < 4; e++){
      h[e]   = (v[c*2][e]  -mean)*rstd*g0[e] + b0[e];
      h[e+4] = (v[c*2+1][e]-mean)*rstd*g1[e] + b1[e];
    }
    if (SPLIT){
      f16x8 Hv, Lv;
      #pragma unroll
      for (int e = 0; e < 8; e++){
        _Float16 hh = (_Float16)h[e];
        Hv[e] = hh; Lv[e] = (_Float16)(h[e] - (float)hh);
      }
      const size_t addr = (size_t)row*1024 + c*512 + (lane>>3)*64 + (((lane&7)*8) ^ ((row&7)*8));
      *(f16x8*)&Oh[addr] = Hv;
      *(f16x8*)&Ol[addr] = Lv;
    } else {
      f32x4 o0, o1;
      #pragma unroll
      for (int e = 0; e < 4; e++){ o0[e] = h[e]; o1[e] = h[e+4]; }
      *(f32x4*)(outf + (size_t)row*1024 + col) = o0;
      *(f32x4*)(outf + (size_t)row*1024 + col + 4) = o1;
    }
  }
}

// ---------------- bitlinear GEMM: C[2048,1024] = (Ah+Al).Wb^T * beta ----------------
// BM=BN=64, BK=64, 4 waves (2Mx2N, wave-tile 32x32), double-buffered gload staging.
// MODE 0: GELU -> split fp16 out (swizzled A-layout). MODE 1: += into fp32 residual.
template<int MODE>
__global__ __launch_bounds__(256) void k_gemm(const _Float16* __restrict__ Ah, const _Float16* __restrict__ Al,
                                              const _Float16* __restrict__ Wg,
                                              float* __restrict__ out32,
                                              _Float16* __restrict__ Oh, _Float16* __restrict__ Ol,
                                              const double* __restrict__ dabs_slot){
  __shared__ _Float16 smb[24576];   // 2 x (A-hi 4096 + A-lo 4096 + B 4096)
  const int tid = threadIdx.x, w = tid>>6, l = tid&63, g = l>>4, r16 = l&15;
  const int wm = w>>1, wn = w&1;
  const int n0 = blockIdx.x*64, m0 = blockIdx.y*64;
  const float scale = (float)(*dabs_slot * (1.0/1048576.0));
  const int swr = (r16&7)*8;
  f32x4 acc[2][2] = {};
  #define STAGE(buf, k0) { _Float16* Bp = smb + (buf)*12288;                              \
    _Pragma("unroll")                                                                     \
    for (int j = 0; j < 2; j++){                                                          \
      const int cb = (j*4 + w)*64; const int c = cb + l;                                  \
      const int r = c>>3; const int cc = (c&7)*8;                                         \
      gload_lds16(Ah + (size_t)(m0 + r)*1024 + (k0) + cc, Bp + cb*8);                     \
      gload_lds16(Al + (size_t)(m0 + r)*1024 + (k0) + cc, Bp + 4096 + cb*8);              \
      gload_lds16(Wg + (size_t)(n0 + r)*1024 + (k0) + cc, Bp + 8192 + cb*8);              \
    } }
  STAGE(0, 0);
  __syncthreads();
  for (int t = 0; t < 16; t++){
    if (t < 15) STAGE((t+1)&1, (t+1)*64);
    const _Float16* Bp = smb + (t&1)*12288;
    #pragma unroll
    for (int kk = 0; kk < 2; kk++){
      f16x8 ah[2], al[2], bf[2];
      const int col = (kk*32 + g*8) ^ swr;
      #pragma unroll
      for (int mi = 0; mi < 2; mi++){
        const int row = wm*32 + mi*16 + r16;
        ah[mi] = *(const f16x8*)&Bp[row*64 + col];
        al[mi] = *(const f16x8*)&Bp[4096 + row*64 + col];
      }
      #pragma unroll
      for (int ni = 0; ni < 2; ni++){
        const int row = wn*32 + ni*16 + r16;
        bf[ni] = *(const f16x8*)&Bp[8192 + row*64 + col];
      }
      #pragma unroll
      for (int mi = 0; mi < 2; mi++)
        #pragma unroll
        for (int ni = 0; ni < 2; ni++){
          acc[mi][ni] = mfma16h(ah[mi], bf[ni], acc[mi][ni]);
          acc[mi][ni] = mfma16h(al[mi], bf[ni], acc[mi][ni]);
        }
    }
    __syncthreads();
  }
  #undef STAGE
  #pragma unroll
  for (int mi = 0; mi < 2; mi++)
    #pragma unroll
    for (int ni = 0; ni < 2; ni++)
      #pragma unroll
      for (int i = 0; i < 4; i++){
        const int rr = m0 + wm*32 + mi*16 + g*4 + i;
        const int cc = n0 + wn*32 + ni*16 + r16;
        float vv = acc[mi][ni][i] * scale;
        if (MODE == 0){
          vv = 0.5f*vv*(1.f + erff(vv*0.70710678118f));
          _Float16 hh = (_Float16)vv;
          const size_t addr = (size_t)rr*1024 + (cc & ~63) + ((cc & 63) ^ ((rr&7)*8));
          Oh[addr] = hh;
          Ol[addr] = (_Float16)(vv - (float)hh);
        } else {
          out32[(size_t)rr*1024 + cc] += vv;
        }
      }
}

extern "C" void kernel_launch(void* const* d_in, const int* in_sizes, int n_in,
                              void* d_out, int out_size, void* d_ws, size_t ws_size,
                              hipStream_t stream){
  const float* x_in = (const float*)d_in[0];
  const float* ln_g = (const float*)d_in[1];
  const float* ln_b = (const float*)d_in[2];
  const float* w1   = (const float*)d_in[3];
  const float* w2   = (const float*)d_in[4];
  const float* fg   = (const float*)d_in[5];
  const float* fb   = (const float*)d_in[6];

  char* ws = (char*)d_ws;
  double*   dsum  = (double*)ws;            // 12
  double*   dabs  = (double*)(ws + 96);     // 12
  _Float16* wb = (_Float16*)(ws + 256);     // 12 * 1M fp16 = 24 MB
  size_t o = 256 + 12ull*1048576ull*2ull;
  float* xA = (float*)(ws + o); o += 2048ull*1024*4;
  float* xB = (float*)(ws + o); o += 2048ull*1024*4;
  _Float16* Kh = (_Float16*)(ws + o); o += 2048ull*1024*2;
  _Float16* Kl = (_Float16*)(ws + o); o += 2048ull*1024*2;
  _Float16* Vh = (_Float16*)(ws + o); o += 2048ull*1024*2;
  _Float16* Vl = (_Float16*)(ws + o); o += 2048ull*1024*2;
  _Float16* Ahb = (_Float16*)(ws + o); o += 2048ull*1024*2;
  _Float16* Alb = (_Float16*)(ws + o); o += 2048ull*1024*2;
  _Float16* Ghb = (_Float16*)(ws + o); o += 2048ull*1024*2;
  _Float16* Glb = (_Float16*)(ws + o); o += 2048ull*1024*2;

  hipMemsetAsync(ws, 0, 256, stream);
  k_wstats  <<<dim3(32,12), 256, 0, stream>>>(w1, w2, dsum, dabs);
  k_binarize<<<6144,        256, 0, stream>>>(w1, w2, dsum, wb);

  const float* xc = x_in;
  for (int i = 0; i < 6; i++){
    float* xn = (i & 1) ? xB : xA;
    k_presplit<<<dim3(16,32), 256, 0, stream>>>(xc, Kh, Kl, Vh, Vl);
    k_attn    <<<dim3(32,16), 256, 0, stream>>>(Kh, Kl, Vh, Vl, xc, xn);
    k_ln<1>   <<<512, 256, 0, stream>>>(xn, ln_g + (size_t)i*1024, ln_b + (size_t)i*1024,
                                        nullptr, Ahb, Alb);
    k_gemm<0> <<<dim3(16,32), 256, 0, stream>>>(Ahb, Alb, wb + (size_t)i*1048576,
                                                nullptr, Ghb, Glb, &dabs[i]);
    k_gemm<1> <<<dim3(16,32), 256, 0, stream>>>(Ghb, Glb, wb + (size_t)(6+i)*1048576,
                                                xn, nullptr, nullptr, &dabs[6+i]);
    xc = xn;
  }
  k_ln<0><<<512, 256, 0, stream>>>(xc, fg, fb, (float*)d_out, nullptr, nullptr);
}